// Round 1
// baseline (733.941 us; speedup 1.0000x reference)
//
#include <hip/hip_runtime.h>
#include <hip/hip_bf16.h>
#include <cstdint>

typedef __attribute__((ext_vector_type(8))) short short8_t;   // 8 x bf16
typedef __attribute__((ext_vector_type(4))) float f32x4_t;    // MFMA acc

#define AS1 __attribute__((address_space(1)))
#define AS3 __attribute__((address_space(3)))

__device__ __forceinline__ void gload_lds16(const void* g, void* l) {
  __builtin_amdgcn_global_load_lds((const AS1 void*)g, (AS3 void*)l, 16, 0, 0);
}

__device__ __forceinline__ short8_t ld8(const __hip_bfloat16* p) {
  return *(const short8_t*)p;
}

// ---------------- f32 -> bf16 convert ----------------
__global__ __launch_bounds__(256) void k_convert(const float* __restrict__ in,
                                                 __hip_bfloat16* __restrict__ out, int n) {
  int i = (blockIdx.x * 256 + threadIdx.x) * 8;
  if (i >= n) return;
  union { short8_t v; __hip_bfloat16 h[8]; } u;
#pragma unroll
  for (int j = 0; j < 8; ++j) u.h[j] = __float2bfloat16(in[i + j]);
  *(short8_t*)(out + i) = u.v;
}

// ---------------- transpose + convert: in[R][C] f32 -> out[C][R] bf16 ----------------
__global__ __launch_bounds__(256) void k_transpose(const float* __restrict__ in,
                                                   __hip_bfloat16* __restrict__ out,
                                                   int R, int C) {
  __shared__ float t[64][65];
  int nct = C >> 6;
  int ct = blockIdx.x % nct, rt = blockIdx.x / nct;
  int r0 = rt << 6, c0 = ct << 6;
#pragma unroll
  for (int i = 0; i < 16; ++i) {
    int idx = i * 256 + threadIdx.x;
    int r = idx >> 6, c = idx & 63;
    t[r][c] = in[(size_t)(r0 + r) * C + c0 + c];
  }
  __syncthreads();
#pragma unroll
  for (int i = 0; i < 16; ++i) {
    int idx = i * 256 + threadIdx.x;
    int c = idx >> 6, r = idx & 63;
    out[(size_t)(c0 + c) * R + r0 + r] = __float2bfloat16(t[r][c]);
  }
}

// ---------------- GEMM: A[M][K] bf16 rm, Bt[N][K] bf16 rm -> C[M][N] (bf16 or f32), alpha-scaled
// m97 structure: 128x128 tile, BK=32, global_load_lds w=16, 4 waves, 4x4 16x16x32 frags/wave.
template<int OUT_F32>
__global__ __launch_bounds__(256) void k_gemm_bt(const __hip_bfloat16* __restrict__ A,
                                                 const __hip_bfloat16* __restrict__ Bt,
                                                 void* __restrict__ C,
                                                 int M, int N, int K, float alpha) {
  __shared__ __align__(16) __hip_bfloat16 Al[128 * 32];
  __shared__ __align__(16) __hip_bfloat16 Bl[128 * 32];
  int nbx = N >> 7;
  int bx = blockIdx.x % nbx, by = blockIdx.x / nbx;
  int tid = threadIdx.x, lane = tid & 63, w = tid >> 6;
  int wr = (w >> 1) << 6, wc = (w & 1) << 6;
  f32x4_t acc[4][4] = {};
  const __hip_bfloat16* Ag = A + (size_t)(by * 128) * K;
  const __hip_bfloat16* Bg = Bt + (size_t)(bx * 128) * K;
  int srow = w * 32 + (lane >> 2);   // staged row within 32-row wave slice
  int scol = (lane & 3) * 8;
  for (int k0 = 0; k0 < K; k0 += 32) {
    __syncthreads();
    gload_lds16(Ag + (size_t)srow * K + k0 + scol,        Al + (w * 32) * 32);
    gload_lds16(Ag + (size_t)(srow + 16) * K + k0 + scol, Al + (w * 32 + 16) * 32);
    gload_lds16(Bg + (size_t)srow * K + k0 + scol,        Bl + (w * 32) * 32);
    gload_lds16(Bg + (size_t)(srow + 16) * K + k0 + scol, Bl + (w * 32 + 16) * 32);
    __syncthreads();   // compiler drains vmcnt before s_barrier
    short8_t af[4], bf[4];
#pragma unroll
    for (int m = 0; m < 4; ++m)
      af[m] = ld8(Al + (wr + 16 * m + (lane & 15)) * 32 + 8 * (lane >> 4));
#pragma unroll
    for (int n = 0; n < 4; ++n)
      bf[n] = ld8(Bl + (wc + 16 * n + (lane & 15)) * 32 + 8 * (lane >> 4));
#pragma unroll
    for (int m = 0; m < 4; ++m)
#pragma unroll
      for (int n = 0; n < 4; ++n)
        acc[m][n] = __builtin_amdgcn_mfma_f32_16x16x32_bf16(af[m], bf[n], acc[m][n], 0, 0, 0);
  }
  int r0 = by * 128 + wr + 4 * (lane >> 4);
  int c0 = bx * 128 + wc + (lane & 15);
#pragma unroll
  for (int m = 0; m < 4; ++m)
#pragma unroll
    for (int n = 0; n < 4; ++n)
#pragma unroll
      for (int i = 0; i < 4; ++i) {
        size_t o = (size_t)(r0 + 16 * m + i) * N + c0 + 16 * n;
        float v = acc[m][n][i] * alpha;
        if (OUT_F32) ((float*)C)[o] = v;
        else ((__hip_bfloat16*)C)[o] = __float2bfloat16(v);
      }
}

// ---------------- YaRN RoPE in-place on [4096][H*64] bf16, fused output scale ----------------
__global__ __launch_bounds__(256) void k_rope(__hip_bfloat16* __restrict__ buf, float outscale) {
  int idx = blockIdx.x * 256 + threadIdx.x;   // 4096*16*32 threads
  int i = idx & 31;
  int h = (idx >> 5) & 15;
  int row = idx >> 9;           // b*T + t
  int t = row & 2047;           // T = 2048
  float fi = (float)i;
  float base_inv = expf(fi * (-9.210340371976184f / 32.0f));  // 10000^(-i/32)
  float ramp = fminf(fmaxf((fi - 1.0f) * (1.0f / 31.0f), 0.0f), 1.0f);
  float invf = base_inv * ((1.0f - ramp) + (1.0f / 32.0f) * ramp);
  float ang = (float)t * invf;
  float cs = cosf(ang), sn = sinf(ang);
  size_t o = (size_t)row * 1024 + h * 64 + i;
  float x1 = __bfloat162float(buf[o]);
  float x2 = __bfloat162float(buf[o + 32]);
  buf[o]      = __float2bfloat16((x1 * cs - x2 * sn) * outscale);
  buf[o + 32] = __float2bfloat16((x2 * cs + x1 * sn) * outscale);
}

// ---------------- flash-style sparse attention ----------------
// Block = (b, h, q-tile of 64). 4 waves x 16 q-rows. K_cat = [k_c(128) | k_r(64)].
// q_c pre-scaled by SCALE; q_r pre-scaled by SCALE_ROPE*YF; k_r pre-scaled by YF.
__global__ __launch_bounds__(256) void k_attn(const __hip_bfloat16* __restrict__ qc,
                                              const __hip_bfloat16* __restrict__ kc,
                                              const __hip_bfloat16* __restrict__ vc,
                                              const __hip_bfloat16* __restrict__ qr,
                                              const __hip_bfloat16* __restrict__ kr,
                                              __hip_bfloat16* __restrict__ ao) {
  const int T = 2048;
  int qt = blockIdx.x & 31;
  int h  = (blockIdx.x >> 5) & 15;
  int b  = blockIdx.x >> 9;
  int tid = threadIdx.x, lane = tid & 63, w = tid >> 6;
  int q0 = qt * 64;

  __shared__ __align__(16) __hip_bfloat16 Kl[64 * 200];    // K_cat tile, padded (192->200)
  __shared__ __align__(16) __hip_bfloat16 Vt[128 * 72];    // V transposed [dh][key], padded
  __shared__ __align__(16) __hip_bfloat16 Pl[4][16 * 72];  // per-wave P relayout

  // Q fragments (held in registers for the whole kernel)
  int qrow = q0 + w * 16 + (lane & 15);
  size_t qb = (size_t)b * T + qrow;
  short8_t qf[6];
#pragma unroll
  for (int c = 0; c < 4; ++c)
    qf[c] = ld8(qc + qb * 2048 + h * 128 + 32 * c + 8 * (lane >> 4));
#pragma unroll
  for (int c = 0; c < 2; ++c)
    qf[4 + c] = ld8(qr + qb * 1024 + h * 64 + 32 * c + 8 * (lane >> 4));

  f32x4_t oacc[8] = {};
  float mrow[4], lrow[4];
#pragma unroll
  for (int i = 0; i < 4; ++i) { mrow[i] = -1e30f; lrow[i] = 0.0f; }

  for (int kt = 0; kt <= qt; ++kt) {
    int k0 = kt * 64;
    // stage K_cat: 64 rows x 192 dims
#pragma unroll
    for (int i = 0; i < 6; ++i) {
      int ch = i * 256 + tid;           // 0..1535, 8-elem chunks
      int r = ch / 24;
      int d = (ch % 24) * 8;
      size_t krow = (size_t)b * T + k0 + r;
      const __hip_bfloat16* src = (d < 128)
          ? kc + krow * 2048 + h * 128 + d
          : kr + krow * 1024 + h * 64 + (d - 128);
      *(short8_t*)(Kl + r * 200 + d) = ld8(src);
    }
    // stage V transposed: Vt[dh][key]
#pragma unroll
    for (int i = 0; i < 4; ++i) {
      int ch = i * 256 + tid;           // 0..1023
      int key = ch >> 4;
      int d0 = (ch & 15) * 8;
      size_t vrow = (size_t)b * T + k0 + key;
      union { short8_t v; __hip_bfloat16 hh[8]; } u;
      u.v = ld8(vc + vrow * 2048 + h * 128 + d0);
#pragma unroll
      for (int j = 0; j < 8; ++j) Vt[(d0 + j) * 72 + key] = u.hh[j];
    }
    __syncthreads();

    // S = Q_cat @ K_cat^T  (16 rows x 64 keys per wave)
    f32x4_t sacc[4] = {};
#pragma unroll
    for (int n = 0; n < 4; ++n)
#pragma unroll
      for (int c = 0; c < 6; ++c) {
        short8_t bfr = ld8(Kl + (16 * n + (lane & 15)) * 200 + 32 * c + 8 * (lane >> 4));
        sacc[n] = __builtin_amdgcn_mfma_f32_16x16x32_bf16(qf[c], bfr, sacc[n], 0, 0, 0);
      }

    // mask + online softmax. C layout: row = 4*(lane>>4)+i, col = lane&15.
    int rbase = q0 + w * 16 + 4 * (lane >> 4);
    int cbase = k0 + (lane & 15);
    float p[4][4];
    float mt[4];
#pragma unroll
    for (int i = 0; i < 4; ++i) mt[i] = -1e30f;
#pragma unroll
    for (int n = 0; n < 4; ++n) {
      int k = cbase + 16 * n;
#pragma unroll
      for (int i = 0; i < 4; ++i) {
        int r = rbase + i;
        bool ok = (k <= r) && ((r - k <= 256) || ((k & 63) == 0) || (k < 128));
        float s = ok ? sacc[n][i] : -1e30f;
        p[n][i] = s;
        mt[i] = fmaxf(mt[i], s);
      }
    }
    for (int d = 1; d < 16; d <<= 1)
#pragma unroll
      for (int i = 0; i < 4; ++i) mt[i] = fmaxf(mt[i], __shfl_xor(mt[i], d, 64));
    float al[4], rs[4];
#pragma unroll
    for (int i = 0; i < 4; ++i) {
      float mnew = fmaxf(mrow[i], mt[i]);
      al[i] = __expf(mrow[i] - mnew);
      mrow[i] = mnew;
      rs[i] = 0.0f;
    }
#pragma unroll
    for (int n = 0; n < 4; ++n)
#pragma unroll
      for (int i = 0; i < 4; ++i) {
        float e = __expf(p[n][i] - mrow[i]);
        p[n][i] = e;
        rs[i] += e;
      }
    for (int d = 1; d < 16; d <<= 1)
#pragma unroll
      for (int i = 0; i < 4; ++i) rs[i] += __shfl_xor(rs[i], d, 64);
#pragma unroll
    for (int i = 0; i < 4; ++i) lrow[i] = lrow[i] * al[i] + rs[i];
#pragma unroll
    for (int n = 0; n < 8; ++n)
#pragma unroll
      for (int i = 0; i < 4; ++i) oacc[n][i] *= al[i];

    // P -> LDS (bf16) for A-fragment relayout
#pragma unroll
    for (int n = 0; n < 4; ++n)
#pragma unroll
      for (int i = 0; i < 4; ++i)
        Pl[w][(4 * (lane >> 4) + i) * 72 + 16 * n + (lane & 15)] = __float2bfloat16(p[n][i]);
    __syncthreads();

    // O += P @ V   (16 x 128 per wave)
#pragma unroll
    for (int ks = 0; ks < 2; ++ks) {
      short8_t pa = ld8(Pl[w] + (lane & 15) * 72 + 32 * ks + 8 * (lane >> 4));
#pragma unroll
      for (int n = 0; n < 8; ++n) {
        short8_t bv = ld8(Vt + (16 * n + (lane & 15)) * 72 + 32 * ks + 8 * (lane >> 4));
        oacc[n] = __builtin_amdgcn_mfma_f32_16x16x32_bf16(pa, bv, oacc[n], 0, 0, 0);
      }
    }
    __syncthreads();   // before next tile overwrites Kl/Vt
  }

  // epilogue: O / l -> bf16, layout [(b*T + r)][h*128 + dh]
#pragma unroll
  for (int n = 0; n < 8; ++n)
#pragma unroll
    for (int i = 0; i < 4; ++i) {
      int r = q0 + w * 16 + 4 * (lane >> 4) + i;
      int cdh = 16 * n + (lane & 15);
      float v = oacc[n][i] / lrow[i];
      ao[((size_t)b * T + r) * 2048 + h * 128 + cdh] = __float2bfloat16(v);
    }
}

// ---------------- host ----------------
extern "C" void kernel_launch(void* const* d_in, const int* in_sizes, int n_in,
                              void* d_out, int out_size, void* d_ws, size_t ws_size,
                              hipStream_t stream) {
  const float* x     = (const float*)d_in[0];
  const float* w_q   = (const float*)d_in[1];
  const float* w_dkv = (const float*)d_in[2];
  const float* w_uk  = (const float*)d_in[3];
  const float* w_uv  = (const float*)d_in[4];
  const float* w_qp  = (const float*)d_in[5];
  const float* w_kp  = (const float*)d_in[6];
  const float* w_o   = (const float*)d_in[7];
  float* out = (float*)d_out;

  char* ws = (char*)d_ws;
  size_t off = 0;
  auto alloc = [&](size_t elems) {
    __hip_bfloat16* p = (__hip_bfloat16*)(ws + off);
    off += ((elems * 2 + 255) & ~(size_t)255);
    return p;
  };
  __hip_bfloat16* xb    = alloc(8388608);   // x bf16 [4096][2048]
  __hip_bfloat16* wqT   = alloc(4194304);   // w_q^T  [2048][2048]
  __hip_bfloat16* wdkvT = alloc(1048576);   // [512][2048]
  __hip_bfloat16* wukT  = alloc(1048576);   // [2048][512]
  __hip_bfloat16* wuvT  = alloc(1048576);   // [2048][512]
  __hip_bfloat16* wqpT  = alloc(2097152);   // [1024][2048]
  __hip_bfloat16* wkpT  = alloc(2097152);   // [1024][2048]
  __hip_bfloat16* woT   = alloc(4194304);   // [2048][2048]
  __hip_bfloat16* qcb   = alloc(8388608);   // q_c * SCALE
  __hip_bfloat16* ckv   = alloc(2097152);   // [4096][512]
  __hip_bfloat16* kcb   = alloc(8388608);
  __hip_bfloat16* vcb   = alloc(8388608);
  __hip_bfloat16* qrb   = alloc(4194304);   // [4096][1024]
  __hip_bfloat16* krb   = alloc(4194304);
  __hip_bfloat16* aob   = alloc(8388608);   // attention out bf16

  const float SCALE    = 0.08838834764831845f;        // 1/sqrt(128)
  const float QR_SCALE = 0.16832169878499666f;        // (1/8) * yarn_factor
  const float KR_SCALE = 1.3465735902799727f;         // yarn_factor

  k_convert<<<4096, 256, 0, stream>>>(x, xb, 8388608);
  k_transpose<<<32 * 32, 256, 0, stream>>>(w_q,   wqT,   2048, 2048);
  k_transpose<<<32 * 8,  256, 0, stream>>>(w_dkv, wdkvT, 2048, 512);
  k_transpose<<<8 * 32,  256, 0, stream>>>(w_uk,  wukT,  512, 2048);
  k_transpose<<<8 * 32,  256, 0, stream>>>(w_uv,  wuvT,  512, 2048);
  k_transpose<<<32 * 16, 256, 0, stream>>>(w_qp,  wqpT,  2048, 1024);
  k_transpose<<<32 * 16, 256, 0, stream>>>(w_kp,  wkpT,  2048, 1024);
  k_transpose<<<32 * 32, 256, 0, stream>>>(w_o,   woT,   2048, 2048);

  k_gemm_bt<0><<<32 * 16, 256, 0, stream>>>(xb,  wqT,   qcb, 4096, 2048, 2048, SCALE);
  k_gemm_bt<0><<<32 * 4,  256, 0, stream>>>(xb,  wdkvT, ckv, 4096, 512,  2048, 1.0f);
  k_gemm_bt<0><<<32 * 16, 256, 0, stream>>>(ckv, wukT,  kcb, 4096, 2048, 512,  1.0f);
  k_gemm_bt<0><<<32 * 16, 256, 0, stream>>>(ckv, wuvT,  vcb, 4096, 2048, 512,  1.0f);
  k_gemm_bt<0><<<32 * 8,  256, 0, stream>>>(xb,  wqpT,  qrb, 4096, 1024, 2048, 1.0f);
  k_gemm_bt<0><<<32 * 8,  256, 0, stream>>>(xb,  wkpT,  krb, 4096, 1024, 2048, 1.0f);

  k_rope<<<8192, 256, 0, stream>>>(qrb, QR_SCALE);
  k_rope<<<8192, 256, 0, stream>>>(krb, KR_SCALE);

  k_attn<<<1024, 256, 0, stream>>>(qcb, kcb, vcb, qrb, krb, aob);

  k_gemm_bt<1><<<32 * 16, 256, 0, stream>>>(aob, woT, out, 4096, 2048, 2048, 1.0f);
}

// Round 2
// 415.862 us; speedup vs baseline: 1.7649x; 1.7649x over previous
//
#include <hip/hip_runtime.h>
#include <hip/hip_bf16.h>
#include <cstdint>

typedef __attribute__((ext_vector_type(8))) short short8_t;   // 8 x bf16
typedef __attribute__((ext_vector_type(4))) float f32x4_t;    // MFMA acc

#define AS1 __attribute__((address_space(1)))
#define AS3 __attribute__((address_space(3)))

__device__ __forceinline__ void gload_lds16(const void* g, void* l) {
  __builtin_amdgcn_global_load_lds((const AS1 void*)g, (AS3 void*)l, 16, 0, 0);
}

__device__ __forceinline__ short8_t ld8(const __hip_bfloat16* p) {
  return *(const short8_t*)p;
}

// ---------------- f32 -> bf16 convert ----------------
__global__ __launch_bounds__(256) void k_convert(const float* __restrict__ in,
                                                 __hip_bfloat16* __restrict__ out, int n) {
  int i = (blockIdx.x * 256 + threadIdx.x) * 8;
  if (i >= n) return;
  union { short8_t v; __hip_bfloat16 h[8]; } u;
#pragma unroll
  for (int j = 0; j < 8; ++j) u.h[j] = __float2bfloat16(in[i + j]);
  *(short8_t*)(out + i) = u.v;
}

// ---------------- transpose + convert: in[R][C] f32 -> out[C][R] bf16 ----------------
__global__ __launch_bounds__(256) void k_transpose(const float* __restrict__ in,
                                                   __hip_bfloat16* __restrict__ out,
                                                   int R, int C) {
  __shared__ float t[64][65];
  int nct = C >> 6;
  int ct = blockIdx.x % nct, rt = blockIdx.x / nct;
  int r0 = rt << 6, c0 = ct << 6;
#pragma unroll
  for (int i = 0; i < 16; ++i) {
    int idx = i * 256 + threadIdx.x;
    int r = idx >> 6, c = idx & 63;
    t[r][c] = in[(size_t)(r0 + r) * C + c0 + c];
  }
  __syncthreads();
#pragma unroll
  for (int i = 0; i < 16; ++i) {
    int idx = i * 256 + threadIdx.x;
    int c = idx >> 6, r = idx & 63;
    out[(size_t)(c0 + c) * R + r0 + r] = __float2bfloat16(t[r][c]);
  }
}

// ---------------- bf16 V transpose: vcb [B*T][H*128] -> vT [B*H][128][T] ----------------
__global__ __launch_bounds__(256) void k_vtrans(const __hip_bfloat16* __restrict__ vcb,
                                                __hip_bfloat16* __restrict__ vT) {
  __shared__ __hip_bfloat16 t[64][72];
  int tt = blockIdx.x & 31;          // t-tile (2048/64)
  int dt = (blockIdx.x >> 5) & 1;    // dh-tile (128/64)
  int bh = blockIdx.x >> 6;          // b*16 + h
  int b = bh >> 4, h = bh & 15;
  int tid = threadIdx.x;
#pragma unroll
  for (int i = 0; i < 2; ++i) {
    int ch = i * 256 + tid;                       // 512 chunks
    int r = ch >> 3, c8 = (ch & 7) * 8;           // r: t-local, c8: dh-local
    union { short8_t v; __hip_bfloat16 hh[8]; } u;
    u.v = ld8(vcb + (size_t)(b * 2048 + tt * 64 + r) * 2048 + h * 128 + dt * 64 + c8);
#pragma unroll
    for (int j = 0; j < 8; ++j) t[r][c8 + j] = u.hh[j];
  }
  __syncthreads();
#pragma unroll
  for (int i = 0; i < 2; ++i) {
    int ch = i * 256 + tid;
    int rr = ch >> 3, cc8 = (ch & 7) * 8;         // rr: dh-local, cc8: t-local
    union { short8_t v; __hip_bfloat16 hh[8]; } u;
#pragma unroll
    for (int j = 0; j < 8; ++j) u.hh[j] = t[cc8 + j][rr];
    *(short8_t*)(vT + (size_t)(bh * 128 + dt * 64 + rr) * 2048 + tt * 64 + cc8) = u.v;
  }
}

// ---------------- GEMM: A[M][K] bf16 rm, Bt[N][K] bf16 rm -> C[M][N] (bf16 or f32), alpha-scaled
template<int OUT_F32>
__global__ __launch_bounds__(256) void k_gemm_bt(const __hip_bfloat16* __restrict__ A,
                                                 const __hip_bfloat16* __restrict__ Bt,
                                                 void* __restrict__ C,
                                                 int M, int N, int K, float alpha) {
  __shared__ __align__(16) __hip_bfloat16 Al[128 * 32];
  __shared__ __align__(16) __hip_bfloat16 Bl[128 * 32];
  int nbx = N >> 7;
  int bx = blockIdx.x % nbx, by = blockIdx.x / nbx;
  int tid = threadIdx.x, lane = tid & 63, w = tid >> 6;
  int wr = (w >> 1) << 6, wc = (w & 1) << 6;
  f32x4_t acc[4][4] = {};
  const __hip_bfloat16* Ag = A + (size_t)(by * 128) * K;
  const __hip_bfloat16* Bg = Bt + (size_t)(bx * 128) * K;
  int srow = w * 32 + (lane >> 2);
  int scol = (lane & 3) * 8;
  for (int k0 = 0; k0 < K; k0 += 32) {
    __syncthreads();
    gload_lds16(Ag + (size_t)srow * K + k0 + scol,        Al + (w * 32) * 32);
    gload_lds16(Ag + (size_t)(srow + 16) * K + k0 + scol, Al + (w * 32 + 16) * 32);
    gload_lds16(Bg + (size_t)srow * K + k0 + scol,        Bl + (w * 32) * 32);
    gload_lds16(Bg + (size_t)(srow + 16) * K + k0 + scol, Bl + (w * 32 + 16) * 32);
    __syncthreads();
    short8_t af[4], bf[4];
#pragma unroll
    for (int m = 0; m < 4; ++m)
      af[m] = ld8(Al + (wr + 16 * m + (lane & 15)) * 32 + 8 * (lane >> 4));
#pragma unroll
    for (int n = 0; n < 4; ++n)
      bf[n] = ld8(Bl + (wc + 16 * n + (lane & 15)) * 32 + 8 * (lane >> 4));
#pragma unroll
    for (int m = 0; m < 4; ++m)
#pragma unroll
      for (int n = 0; n < 4; ++n)
        acc[m][n] = __builtin_amdgcn_mfma_f32_16x16x32_bf16(af[m], bf[n], acc[m][n], 0, 0, 0);
  }
  int r0 = by * 128 + wr + 4 * (lane >> 4);
  int c0 = bx * 128 + wc + (lane & 15);
#pragma unroll
  for (int m = 0; m < 4; ++m)
#pragma unroll
    for (int n = 0; n < 4; ++n)
#pragma unroll
      for (int i = 0; i < 4; ++i) {
        size_t o = (size_t)(r0 + 16 * m + i) * N + c0 + 16 * n;
        float v = acc[m][n][i] * alpha;
        if (OUT_F32) ((float*)C)[o] = v;
        else ((__hip_bfloat16*)C)[o] = __float2bfloat16(v);
      }
}

// ---------------- YaRN RoPE in-place on [4096][H*64] bf16, fused output scale ----------------
__global__ __launch_bounds__(256) void k_rope(__hip_bfloat16* __restrict__ buf, float outscale) {
  int idx = blockIdx.x * 256 + threadIdx.x;
  int i = idx & 31;
  int h = (idx >> 5) & 15;
  int row = idx >> 9;
  int t = row & 2047;
  float fi = (float)i;
  float base_inv = expf(fi * (-9.210340371976184f / 32.0f));
  float ramp = fminf(fmaxf((fi - 1.0f) * (1.0f / 31.0f), 0.0f), 1.0f);
  float invf = base_inv * ((1.0f - ramp) + (1.0f / 32.0f) * ramp);
  float ang = (float)t * invf;
  float cs = cosf(ang), sn = sinf(ang);
  size_t o = (size_t)row * 1024 + h * 64 + i;
  float x1 = __bfloat162float(buf[o]);
  float x2 = __bfloat162float(buf[o + 32]);
  buf[o]      = __float2bfloat16((x1 * cs - x2 * sn) * outscale);
  buf[o + 32] = __float2bfloat16((x2 * cs + x1 * sn) * outscale);
}

// ---------------- flash-style SPARSE attention ----------------
// Block = (b, h, q-tile of 64). 4 waves x 16 q-rows.
// Tiles processed: global (kt 0,1) + window (kt qt-4..qt) + ONE compacted dilated
// tile holding keys {64*(2+j), j < nd=qt-6} (each only needs its k%64==0 column).
// Vt is staged from pre-transposed vT with an XOR chunk swizzle (conflict-free).
__global__ __launch_bounds__(256) void k_attn(const __hip_bfloat16* __restrict__ qc,
                                              const __hip_bfloat16* __restrict__ kc,
                                              const __hip_bfloat16* __restrict__ vcb,
                                              const __hip_bfloat16* __restrict__ qr,
                                              const __hip_bfloat16* __restrict__ kr,
                                              const __hip_bfloat16* __restrict__ vT,
                                              __hip_bfloat16* __restrict__ ao) {
  const int T = 2048;
  int qt = blockIdx.x & 31;
  int h  = (blockIdx.x >> 5) & 15;
  int b  = blockIdx.x >> 9;
  int tid = threadIdx.x, lane = tid & 63, w = tid >> 6;
  int L = lane & 15, hi = lane >> 4;
  int q0 = qt * 64;

  __shared__ __align__(16) __hip_bfloat16 Kl[64 * 200];     // K_cat tile [key][192], pad 200
  __shared__ __align__(16) __hip_bfloat16 Vt[128 * 64];     // [dh][key], XOR-swizzled chunks
  __shared__ __align__(16) __hip_bfloat16 Pl[4][16 * 72];   // per-wave P relayout

  char* Vtb = (char*)Vt;
  const __hip_bfloat16* vTb = vT + (size_t)(b * 16 + h) * 128 * 2048;

  // Q fragments in registers for the whole kernel
  int qrow = q0 + w * 16 + L;
  size_t qb = (size_t)b * T + qrow;
  short8_t qf[6];
#pragma unroll
  for (int c = 0; c < 4; ++c)
    qf[c] = ld8(qc + qb * 2048 + h * 128 + 32 * c + 8 * hi);
#pragma unroll
  for (int c = 0; c < 2; ++c)
    qf[4 + c] = ld8(qr + qb * 1024 + h * 64 + 32 * c + 8 * hi);

  f32x4_t oacc[8] = {};
  float mrow[4], lrow[4];
#pragma unroll
  for (int i = 0; i < 4; ++i) { mrow[i] = -1e30f; lrow[i] = 0.0f; }

  int nd = qt - 6;                      // compacted dilated key count (may be <=0)
  int ntiles = (qt <= 6) ? (qt + 1) : (8 + (nd > 0 ? 1 : 0) - 1);  // not used; loop below

  // iterate: full tiles (kt<=1 || kt>=qt-4), then compact tile (tile id -1 marker)
  for (int step = 0; step <= qt + 1; ++step) {
    bool compact = (step == qt + 1);
    if (compact && nd <= 0) break;
    int kt = step;
    if (!compact && kt > 1 && kt < qt - 4) continue;   // skipped (covered by compact)
    int k0 = kt * 64;

    // ---- stage K_cat ----
    if (!compact) {
#pragma unroll
      for (int i = 0; i < 6; ++i) {
        int ch = i * 256 + tid;
        int r = ch / 24;
        int d = (ch % 24) * 8;
        size_t krow = (size_t)b * T + k0 + r;
        const __hip_bfloat16* src = (d < 128)
            ? kc + krow * 2048 + h * 128 + d
            : kr + krow * 1024 + h * 64 + (d - 128);
        *(short8_t*)(Kl + r * 200 + d) = ld8(src);
      }
      // ---- stage V (from vT, vectorized, XOR chunk swizzle) ----
#pragma unroll
      for (int i = 0; i < 4; ++i) {
        int ch = i * 256 + tid;                 // 1024 chunks: 128 rows x 8
        int row = ch >> 3, c = ch & 7;
        int swc = c ^ (row & 7);
        *(short8_t*)(Vtb + row * 128 + 16 * swc) = ld8(vTb + (size_t)row * 2048 + k0 + c * 8);
      }
    } else {
      // compact dilated tile: keys 64*(2+j), j < nd (nd <= 25)
#pragma unroll
      for (int i = 0; i < 6; ++i) {
        int ch = i * 256 + tid;
        int r = ch / 24;
        int d = (ch % 24) * 8;
        int srcr = (r < nd) ? 64 * (2 + r) : 0;
        size_t krow = (size_t)b * T + srcr;
        const __hip_bfloat16* src = (d < 128)
            ? kc + krow * 2048 + h * 128 + d
            : kr + krow * 1024 + h * 64 + (d - 128);
        *(short8_t*)(Kl + r * 200 + d) = ld8(src);
      }
      // V gather: rows from vcb, scalar transposed scatter (small: nd<=25 keys)
#pragma unroll
      for (int i = 0; i < 2; ++i) {
        int ch = i * 256 + tid;                 // 512: 32 keys x 16 chunks
        int j = ch >> 4, d0 = (ch & 15) * 8;
        if (j < nd) {
          union { short8_t v; __hip_bfloat16 hh[8]; } u;
          u.v = ld8(vcb + (size_t)(b * 2048 + 64 * (2 + j)) * 2048 + h * 128 + d0);
#pragma unroll
          for (int jj = 0; jj < 8; ++jj) {
            int dh = d0 + jj;
            int swc = (j >> 3) ^ (dh & 7);
            *(__hip_bfloat16*)(Vtb + dh * 128 + 16 * swc + 2 * (j & 7)) = u.hh[jj];
          }
        }
      }
    }
    __syncthreads();

    // ---- S = Q_cat @ K_cat^T ----
    f32x4_t sacc[4] = {};
#pragma unroll
    for (int n = 0; n < 4; ++n)
#pragma unroll
      for (int c = 0; c < 6; ++c) {
        short8_t bfr = ld8(Kl + (16 * n + L) * 200 + 32 * c + 8 * hi);
        sacc[n] = __builtin_amdgcn_mfma_f32_16x16x32_bf16(qf[c], bfr, sacc[n], 0, 0, 0);
      }

    // ---- mask + online softmax ----
    int rbase = q0 + w * 16 + 4 * hi;
    float p[4][4];
    float mt[4];
#pragma unroll
    for (int i = 0; i < 4; ++i) mt[i] = -1e30f;
#pragma unroll
    for (int n = 0; n < 4; ++n) {
      int col = L + 16 * n;
      int k = k0 + col;
#pragma unroll
      for (int i = 0; i < 4; ++i) {
        int r = rbase + i;
        bool ok = compact ? (col < nd)
                          : ((k <= r) && ((r - k <= 256) || ((k & 63) == 0) || (k < 128)));
        float s = ok ? sacc[n][i] : -1e30f;
        p[n][i] = s;
        mt[i] = fmaxf(mt[i], s);
      }
    }
    for (int d = 1; d < 16; d <<= 1)
#pragma unroll
      for (int i = 0; i < 4; ++i) mt[i] = fmaxf(mt[i], __shfl_xor(mt[i], d, 64));
    float al[4], rs[4];
#pragma unroll
    for (int i = 0; i < 4; ++i) {
      float mnew = fmaxf(mrow[i], mt[i]);
      al[i] = __expf(mrow[i] - mnew);
      mrow[i] = mnew;
      rs[i] = 0.0f;
    }
#pragma unroll
    for (int n = 0; n < 4; ++n)
#pragma unroll
      for (int i = 0; i < 4; ++i) {
        float e = __expf(p[n][i] - mrow[i]);
        p[n][i] = e;
        rs[i] += e;
      }
    for (int d = 1; d < 16; d <<= 1)
#pragma unroll
      for (int i = 0; i < 4; ++i) rs[i] += __shfl_xor(rs[i], d, 64);
#pragma unroll
    for (int i = 0; i < 4; ++i) lrow[i] = lrow[i] * al[i] + rs[i];
#pragma unroll
    for (int n = 0; n < 8; ++n)
#pragma unroll
      for (int i = 0; i < 4; ++i) oacc[n][i] *= al[i];

    // ---- P -> LDS (per-wave buffer) ----
#pragma unroll
    for (int n = 0; n < 4; ++n)
#pragma unroll
      for (int i = 0; i < 4; ++i)
        Pl[w][(4 * hi + i) * 72 + 16 * n + L] = __float2bfloat16(p[n][i]);
    __syncthreads();

    // ---- O += P @ V ----
#pragma unroll
    for (int ks = 0; ks < 2; ++ks) {
      short8_t pa = ld8(Pl[w] + L * 72 + 32 * ks + 8 * hi);
#pragma unroll
      for (int n = 0; n < 8; ++n) {
        int vrow = 16 * n + L;
        int chunk = (4 * ks + hi) ^ (vrow & 7);
        short8_t bv = *(const short8_t*)(Vtb + vrow * 128 + 16 * chunk);
        oacc[n] = __builtin_amdgcn_mfma_f32_16x16x32_bf16(pa, bv, oacc[n], 0, 0, 0);
      }
    }
    __syncthreads();
  }

  // ---- epilogue ----
#pragma unroll
  for (int n = 0; n < 8; ++n)
#pragma unroll
    for (int i = 0; i < 4; ++i) {
      int r = q0 + w * 16 + 4 * hi + i;
      int cdh = 16 * n + L;
      float v = oacc[n][i] / lrow[i];
      ao[((size_t)b * T + r) * 2048 + h * 128 + cdh] = __float2bfloat16(v);
    }
}

// ---------------- host ----------------
extern "C" void kernel_launch(void* const* d_in, const int* in_sizes, int n_in,
                              void* d_out, int out_size, void* d_ws, size_t ws_size,
                              hipStream_t stream) {
  const float* x     = (const float*)d_in[0];
  const float* w_q   = (const float*)d_in[1];
  const float* w_dkv = (const float*)d_in[2];
  const float* w_uk  = (const float*)d_in[3];
  const float* w_uv  = (const float*)d_in[4];
  const float* w_qp  = (const float*)d_in[5];
  const float* w_kp  = (const float*)d_in[6];
  const float* w_o   = (const float*)d_in[7];
  float* out = (float*)d_out;

  char* ws = (char*)d_ws;
  size_t off = 0;
  auto alloc = [&](size_t elems) {
    __hip_bfloat16* p = (__hip_bfloat16*)(ws + off);
    off += ((elems * 2 + 255) & ~(size_t)255);
    return p;
  };
  __hip_bfloat16* xb    = alloc(8388608);
  __hip_bfloat16* wqT   = alloc(4194304);
  __hip_bfloat16* wdkvT = alloc(1048576);
  __hip_bfloat16* wukT  = alloc(1048576);
  __hip_bfloat16* wuvT  = alloc(1048576);
  __hip_bfloat16* wqpT  = alloc(2097152);
  __hip_bfloat16* wkpT  = alloc(2097152);
  __hip_bfloat16* woT   = alloc(4194304);
  __hip_bfloat16* qcb   = alloc(8388608);
  __hip_bfloat16* ckv   = alloc(2097152);
  __hip_bfloat16* kcb   = alloc(8388608);
  __hip_bfloat16* vcb   = alloc(8388608);
  __hip_bfloat16* qrb   = alloc(4194304);
  __hip_bfloat16* krb   = alloc(4194304);
  __hip_bfloat16* aob   = alloc(8388608);
  __hip_bfloat16* vT    = alloc(8388608);   // [32][128][2048]

  const float SCALE    = 0.08838834764831845f;
  const float QR_SCALE = 0.16832169878499666f;
  const float KR_SCALE = 1.3465735902799727f;

  k_convert<<<4096, 256, 0, stream>>>(x, xb, 8388608);
  k_transpose<<<32 * 32, 256, 0, stream>>>(w_q,   wqT,   2048, 2048);
  k_transpose<<<32 * 8,  256, 0, stream>>>(w_dkv, wdkvT, 2048, 512);
  k_transpose<<<8 * 32,  256, 0, stream>>>(w_uk,  wukT,  512, 2048);
  k_transpose<<<8 * 32,  256, 0, stream>>>(w_uv,  wuvT,  512, 2048);
  k_transpose<<<32 * 16, 256, 0, stream>>>(w_qp,  wqpT,  2048, 1024);
  k_transpose<<<32 * 16, 256, 0, stream>>>(w_kp,  wkpT,  2048, 1024);
  k_transpose<<<32 * 32, 256, 0, stream>>>(w_o,   woT,   2048, 2048);

  k_gemm_bt<0><<<32 * 16, 256, 0, stream>>>(xb,  wqT,   qcb, 4096, 2048, 2048, SCALE);
  k_gemm_bt<0><<<32 * 4,  256, 0, stream>>>(xb,  wdkvT, ckv, 4096, 512,  2048, 1.0f);
  k_gemm_bt<0><<<32 * 16, 256, 0, stream>>>(ckv, wukT,  kcb, 4096, 2048, 512,  1.0f);
  k_gemm_bt<0><<<32 * 16, 256, 0, stream>>>(ckv, wuvT,  vcb, 4096, 2048, 512,  1.0f);
  k_gemm_bt<0><<<32 * 8,  256, 0, stream>>>(xb,  wqpT,  qrb, 4096, 1024, 2048, 1.0f);
  k_gemm_bt<0><<<32 * 8,  256, 0, stream>>>(xb,  wkpT,  krb, 4096, 1024, 2048, 1.0f);

  k_rope<<<8192, 256, 0, stream>>>(qrb, QR_SCALE);
  k_rope<<<8192, 256, 0, stream>>>(krb, KR_SCALE);

  k_vtrans<<<2048, 256, 0, stream>>>(vcb, vT);

  k_attn<<<1024, 256, 0, stream>>>(qcb, kcb, vcb, qrb, krb, vT, aob);

  k_gemm_bt<1><<<32 * 16, 256, 0, stream>>>(aob, woT, out, 4096, 2048, 2048, 1.0f);
}

// Round 3
// 299.053 us; speedup vs baseline: 2.4542x; 1.3906x over previous
//
#include <hip/hip_runtime.h>
#include <hip/hip_bf16.h>
#include <cstdint>

typedef __attribute__((ext_vector_type(8))) short short8_t;   // 8 x bf16
typedef __attribute__((ext_vector_type(4))) short short4_t;   // 4 x bf16
typedef __attribute__((ext_vector_type(4))) float f32x4_t;    // MFMA acc

#define AS1 __attribute__((address_space(1)))
#define AS3 __attribute__((address_space(3)))

__device__ __forceinline__ void gload_lds16(const void* g, void* l) {
  __builtin_amdgcn_global_load_lds((const AS1 void*)g, (AS3 void*)l, 16, 0, 0);
}

__device__ __forceinline__ short8_t ld8(const __hip_bfloat16* p) {
  return *(const short8_t*)p;
}

// ---------------- f32 -> bf16 convert ----------------
__global__ __launch_bounds__(256) void k_convert(const float* __restrict__ in,
                                                 __hip_bfloat16* __restrict__ out, int n) {
  int i = (blockIdx.x * 256 + threadIdx.x) * 8;
  if (i >= n) return;
  union { short8_t v; __hip_bfloat16 h[8]; } u;
#pragma unroll
  for (int j = 0; j < 8; ++j) u.h[j] = __float2bfloat16(in[i + j]);
  *(short8_t*)(out + i) = u.v;
}

// ---------------- transpose + convert: in[R][C] f32 -> out[C][R] bf16 ----------------
__global__ __launch_bounds__(256) void k_transpose(const float* __restrict__ in,
                                                   __hip_bfloat16* __restrict__ out,
                                                   int R, int C) {
  __shared__ float t[64][65];
  int nct = C >> 6;
  int ct = blockIdx.x % nct, rt = blockIdx.x / nct;
  int r0 = rt << 6, c0 = ct << 6;
#pragma unroll
  for (int i = 0; i < 16; ++i) {
    int idx = i * 256 + threadIdx.x;
    int r = idx >> 6, c = idx & 63;
    t[r][c] = in[(size_t)(r0 + r) * C + c0 + c];
  }
  __syncthreads();
#pragma unroll
  for (int i = 0; i < 16; ++i) {
    int idx = i * 256 + threadIdx.x;
    int c = idx >> 6, r = idx & 63;
    out[(size_t)(c0 + c) * R + r0 + r] = __float2bfloat16(t[r][c]);
  }
}

// ---------------- generic GEMM (used for final w_o): A[M][K] bf16, Bt[N][K] bf16 -> C ----
template<int OUT_F32>
__global__ __launch_bounds__(256) void k_gemm_bt(const __hip_bfloat16* __restrict__ A,
                                                 const __hip_bfloat16* __restrict__ Bt,
                                                 void* __restrict__ C,
                                                 int M, int N, int K, float alpha) {
  __shared__ __align__(16) __hip_bfloat16 Al[128 * 32];
  __shared__ __align__(16) __hip_bfloat16 Bl[128 * 32];
  int nbx = N >> 7;
  int bx = blockIdx.x % nbx, by = blockIdx.x / nbx;
  int tid = threadIdx.x, lane = tid & 63, w = tid >> 6;
  int wr = (w >> 1) << 6, wc = (w & 1) << 6;
  f32x4_t acc[4][4] = {};
  const __hip_bfloat16* Ag = A + (size_t)(by * 128) * K;
  const __hip_bfloat16* Bg = Bt + (size_t)(bx * 128) * K;
  int srow = w * 32 + (lane >> 2);
  int scol = (lane & 3) * 8;
  for (int k0 = 0; k0 < K; k0 += 32) {
    __syncthreads();
    gload_lds16(Ag + (size_t)srow * K + k0 + scol,        Al + (w * 32) * 32);
    gload_lds16(Ag + (size_t)(srow + 16) * K + k0 + scol, Al + (w * 32 + 16) * 32);
    gload_lds16(Bg + (size_t)srow * K + k0 + scol,        Bl + (w * 32) * 32);
    gload_lds16(Bg + (size_t)(srow + 16) * K + k0 + scol, Bl + (w * 32 + 16) * 32);
    __syncthreads();
    short8_t af[4], bf[4];
#pragma unroll
    for (int m = 0; m < 4; ++m)
      af[m] = ld8(Al + (wr + 16 * m + (lane & 15)) * 32 + 8 * (lane >> 4));
#pragma unroll
    for (int n = 0; n < 4; ++n)
      bf[n] = ld8(Bl + (wc + 16 * n + (lane & 15)) * 32 + 8 * (lane >> 4));
#pragma unroll
    for (int m = 0; m < 4; ++m)
#pragma unroll
      for (int n = 0; n < 4; ++n)
        acc[m][n] = __builtin_amdgcn_mfma_f32_16x16x32_bf16(af[m], bf[n], acc[m][n], 0, 0, 0);
  }
  int r0 = by * 128 + wr + 4 * (lane >> 4);
  int c0 = bx * 128 + wc + (lane & 15);
#pragma unroll
  for (int m = 0; m < 4; ++m)
#pragma unroll
    for (int n = 0; n < 4; ++n)
#pragma unroll
      for (int i = 0; i < 4; ++i) {
        size_t o = (size_t)(r0 + 16 * m + i) * N + c0 + 16 * n;
        float v = acc[m][n][i] * alpha;
        if (OUT_F32) ((float*)C)[o] = v;
        else ((__hip_bfloat16*)C)[o] = __float2bfloat16(v);
      }
}

// ---------------- fused projection GEMM 1: xb @ [w_q|w_qp|w_kp|w_dkv]^T ----------------
// N = 4608 (cols: 0-2047 q_c*SCALE, 2048-3071 q_r(rope*QR), 3072-4095 k_r(rope*KR),
// 4096-4607 c_kv). K = 2048.
__global__ __launch_bounds__(256) void k_gemm_proj1(const __hip_bfloat16* __restrict__ A,
                                                    const __hip_bfloat16* __restrict__ Bt,
                                                    __hip_bfloat16* __restrict__ qcb,
                                                    __hip_bfloat16* __restrict__ qrb,
                                                    __hip_bfloat16* __restrict__ krb,
                                                    __hip_bfloat16* __restrict__ ckv) {
  const int K = 2048;
  __shared__ __align__(16) __hip_bfloat16 Al[128 * 32];
  __shared__ __align__(16) __hip_bfloat16 Bl[128 * 32];
  int bx = blockIdx.x % 36, by = blockIdx.x / 36;
  int tid = threadIdx.x, lane = tid & 63, w = tid >> 6;
  int L = lane & 15, hi = lane >> 4;
  int wr = (w >> 1) << 6, wc = (w & 1) << 6;
  f32x4_t acc[4][4] = {};
  const __hip_bfloat16* Ag = A + (size_t)(by * 128) * K;
  const __hip_bfloat16* Bg = Bt + (size_t)(bx * 128) * K;
  int srow = w * 32 + (lane >> 2);
  int scol = (lane & 3) * 8;
  for (int k0 = 0; k0 < K; k0 += 32) {
    __syncthreads();
    gload_lds16(Ag + (size_t)srow * K + k0 + scol,        Al + (w * 32) * 32);
    gload_lds16(Ag + (size_t)(srow + 16) * K + k0 + scol, Al + (w * 32 + 16) * 32);
    gload_lds16(Bg + (size_t)srow * K + k0 + scol,        Bl + (w * 32) * 32);
    gload_lds16(Bg + (size_t)(srow + 16) * K + k0 + scol, Bl + (w * 32 + 16) * 32);
    __syncthreads();
    short8_t af[4], bf[4];
#pragma unroll
    for (int m = 0; m < 4; ++m)
      af[m] = ld8(Al + (wr + 16 * m + L) * 32 + 8 * hi);
#pragma unroll
    for (int n = 0; n < 4; ++n)
      bf[n] = ld8(Bl + (wc + 16 * n + L) * 32 + 8 * hi);
#pragma unroll
    for (int m = 0; m < 4; ++m)
#pragma unroll
      for (int n = 0; n < 4; ++n)
        acc[m][n] = __builtin_amdgcn_mfma_f32_16x16x32_bf16(af[m], bf[n], acc[m][n], 0, 0, 0);
  }
  int r0 = by * 128 + wr + 4 * hi;
  int cb = bx * 128 + wc;             // wave col base, 64-aligned (one head for rope cols)
  if (bx < 16) {
    const float SCALE = 0.08838834764831845f;
#pragma unroll
    for (int m = 0; m < 4; ++m)
#pragma unroll
      for (int n = 0; n < 4; ++n)
#pragma unroll
        for (int i = 0; i < 4; ++i)
          qcb[(size_t)(r0 + 16 * m + i) * 2048 + cb + 16 * n + L] =
              __float2bfloat16(acc[m][n][i] * SCALE);
  } else if (bx < 32) {
    bool isq = bx < 24;
    __hip_bfloat16* dst = isq ? qrb : krb;
    float osc = isq ? 0.16832169878499666f : 1.3465735902799727f;  // SCALE_ROPE*YF : YF
    int cbl = cb - (isq ? 2048 : 3072);
    float invf[2];
#pragma unroll
    for (int p = 0; p < 2; ++p) {
      float fi = (float)(16 * p + L);
      float bi = __expf(fi * -0.28782313662425574f);   // 10000^(-i/32)
      float ramp = fminf(fmaxf((fi - 1.0f) * (1.0f / 31.0f), 0.0f), 1.0f);
      invf[p] = bi * (1.0f - ramp * (31.0f / 32.0f));
    }
#pragma unroll
    for (int m = 0; m < 4; ++m)
#pragma unroll
      for (int i = 0; i < 4; ++i) {
        int row = r0 + 16 * m + i;
        float ft = (float)(row & 2047);
#pragma unroll
        for (int p = 0; p < 2; ++p) {
          float sn, cs;
          __sincosf(ft * invf[p], &sn, &cs);
          float x1 = acc[m][p][i], x2 = acc[m][p + 2][i];
          dst[(size_t)row * 1024 + cbl + 16 * p + L] =
              __float2bfloat16((x1 * cs - x2 * sn) * osc);
          dst[(size_t)row * 1024 + cbl + 32 + 16 * p + L] =
              __float2bfloat16((x2 * cs + x1 * sn) * osc);
        }
      }
  } else {
    int cbl = cb - 4096;
#pragma unroll
    for (int m = 0; m < 4; ++m)
#pragma unroll
      for (int n = 0; n < 4; ++n)
#pragma unroll
        for (int i = 0; i < 4; ++i)
          ckv[(size_t)(r0 + 16 * m + i) * 512 + cbl + 16 * n + L] =
              __float2bfloat16(acc[m][n][i]);
  }
}

// ---------------- fused projection GEMM 2: ckv @ [w_uk|w_uv]^T ----------------
// N = 4096 (cols 0-2047 k_c -> kcb; 2048-4095 v_c -> vcb AND vT transposed). K = 512.
__global__ __launch_bounds__(256) void k_gemm_proj2(const __hip_bfloat16* __restrict__ A,
                                                    const __hip_bfloat16* __restrict__ Bt,
                                                    __hip_bfloat16* __restrict__ kcb,
                                                    __hip_bfloat16* __restrict__ vcb,
                                                    __hip_bfloat16* __restrict__ vT) {
  const int K = 512;
  __shared__ __align__(16) __hip_bfloat16 Al[128 * 32];
  __shared__ __align__(16) __hip_bfloat16 Bl[128 * 32];
  int bx = blockIdx.x & 31, by = blockIdx.x >> 5;
  int tid = threadIdx.x, lane = tid & 63, w = tid >> 6;
  int L = lane & 15, hi = lane >> 4;
  int wr = (w >> 1) << 6, wc = (w & 1) << 6;
  f32x4_t acc[4][4] = {};
  const __hip_bfloat16* Ag = A + (size_t)(by * 128) * K;
  const __hip_bfloat16* Bg = Bt + (size_t)(bx * 128) * K;
  int srow = w * 32 + (lane >> 2);
  int scol = (lane & 3) * 8;
  for (int k0 = 0; k0 < K; k0 += 32) {
    __syncthreads();
    gload_lds16(Ag + (size_t)srow * K + k0 + scol,        Al + (w * 32) * 32);
    gload_lds16(Ag + (size_t)(srow + 16) * K + k0 + scol, Al + (w * 32 + 16) * 32);
    gload_lds16(Bg + (size_t)srow * K + k0 + scol,        Bl + (w * 32) * 32);
    gload_lds16(Bg + (size_t)(srow + 16) * K + k0 + scol, Bl + (w * 32 + 16) * 32);
    __syncthreads();
    short8_t af[4], bf[4];
#pragma unroll
    for (int m = 0; m < 4; ++m)
      af[m] = ld8(Al + (wr + 16 * m + L) * 32 + 8 * hi);
#pragma unroll
    for (int n = 0; n < 4; ++n)
      bf[n] = ld8(Bl + (wc + 16 * n + L) * 32 + 8 * hi);
#pragma unroll
    for (int m = 0; m < 4; ++m)
#pragma unroll
      for (int n = 0; n < 4; ++n)
        acc[m][n] = __builtin_amdgcn_mfma_f32_16x16x32_bf16(af[m], bf[n], acc[m][n], 0, 0, 0);
  }
  int r0 = by * 128 + wr + 4 * hi;
  int cb = bx * 128 + wc;
  if (bx < 16) {
#pragma unroll
    for (int m = 0; m < 4; ++m)
#pragma unroll
      for (int n = 0; n < 4; ++n)
#pragma unroll
        for (int i = 0; i < 4; ++i)
          kcb[(size_t)(r0 + 16 * m + i) * 2048 + cb + 16 * n + L] =
              __float2bfloat16(acc[m][n][i]);
  } else {
#pragma unroll
    for (int m = 0; m < 4; ++m)
#pragma unroll
      for (int n = 0; n < 4; ++n) {
        int vcol = cb - 2048 + 16 * n + L;      // 0..2047: h*128+dh
        int hh = vcol >> 7, dh = vcol & 127;
        int row0 = r0 + 16 * m;                 // 4 consecutive rows, same b
        int b = row0 >> 11, t0 = row0 & 2047;
        union { short4_t v; __hip_bfloat16 h4[4]; } pk;
#pragma unroll
        for (int i = 0; i < 4; ++i) {
          __hip_bfloat16 bv = __float2bfloat16(acc[m][n][i]);
          vcb[(size_t)(row0 + i) * 2048 + vcol] = bv;
          pk.h4[i] = bv;
        }
        *(short4_t*)(vT + ((size_t)((b * 16 + hh) * 128 + dh) * 2048 + t0)) = pk.v;
      }
  }
}

// ---------------- flash-style SPARSE attention ----------------
// Block = (b, h, q-tile of 64), remapped so each XCD works on bh ≡ xcd (mod 8)
// first -> K/V slice (~1.8 MB) stays in that XCD's L2.
__global__ __launch_bounds__(256) void k_attn(const __hip_bfloat16* __restrict__ qc,
                                              const __hip_bfloat16* __restrict__ kc,
                                              const __hip_bfloat16* __restrict__ vcb,
                                              const __hip_bfloat16* __restrict__ qr,
                                              const __hip_bfloat16* __restrict__ kr,
                                              const __hip_bfloat16* __restrict__ vT,
                                              __hip_bfloat16* __restrict__ ao) {
  const int T = 2048;
  // XCD-grouping remap (1024 blocks, 8 XCDs round-robin):
  int bid = blockIdx.x;
  int xcd = bid & 7, r = bid >> 3;
  int j = r >> 5, qt = r & 31;
  int bh = xcd + 8 * j;
  int b = bh >> 4, h = bh & 15;
  int tid = threadIdx.x, lane = tid & 63, w = tid >> 6;
  int L = lane & 15, hi = lane >> 4;
  int q0 = qt * 64;

  __shared__ __align__(16) __hip_bfloat16 Kl[64 * 200];     // K_cat tile [key][192], pad 200
  __shared__ __align__(16) __hip_bfloat16 Vt[128 * 64];     // [dh][key], XOR-swizzled chunks
  __shared__ __align__(16) __hip_bfloat16 Pl[4][16 * 72];   // per-wave P relayout

  char* Vtb = (char*)Vt;
  const __hip_bfloat16* vTb = vT + (size_t)(b * 16 + h) * 128 * 2048;

  int qrow = q0 + w * 16 + L;
  size_t qb = (size_t)b * T + qrow;
  short8_t qf[6];
#pragma unroll
  for (int c = 0; c < 4; ++c)
    qf[c] = ld8(qc + qb * 2048 + h * 128 + 32 * c + 8 * hi);
#pragma unroll
  for (int c = 0; c < 2; ++c)
    qf[4 + c] = ld8(qr + qb * 1024 + h * 64 + 32 * c + 8 * hi);

  f32x4_t oacc[8] = {};
  float mrow[4], lrow[4];
#pragma unroll
  for (int i = 0; i < 4; ++i) { mrow[i] = -1e30f; lrow[i] = 0.0f; }

  int nd = qt - 6;   // compacted dilated key count

  for (int step = 0; step <= qt + 1; ++step) {
    bool compact = (step == qt + 1);
    if (compact && nd <= 0) break;
    int kt = step;
    if (!compact && kt > 1 && kt < qt - 4) continue;
    int k0 = kt * 64;

    if (!compact) {
#pragma unroll
      for (int i = 0; i < 6; ++i) {
        int ch = i * 256 + tid;
        int rr = ch / 24;
        int d = (ch % 24) * 8;
        size_t krow = (size_t)b * T + k0 + rr;
        const __hip_bfloat16* src = (d < 128)
            ? kc + krow * 2048 + h * 128 + d
            : kr + krow * 1024 + h * 64 + (d - 128);
        *(short8_t*)(Kl + rr * 200 + d) = ld8(src);
      }
#pragma unroll
      for (int i = 0; i < 4; ++i) {
        int ch = i * 256 + tid;
        int row = ch >> 3, c = ch & 7;
        int swc = c ^ (row & 7);
        *(short8_t*)(Vtb + row * 128 + 16 * swc) = ld8(vTb + (size_t)row * 2048 + k0 + c * 8);
      }
    } else {
#pragma unroll
      for (int i = 0; i < 6; ++i) {
        int ch = i * 256 + tid;
        int rr = ch / 24;
        int d = (ch % 24) * 8;
        int srcr = (rr < nd) ? 64 * (2 + rr) : 0;
        size_t krow = (size_t)b * T + srcr;
        const __hip_bfloat16* src = (d < 128)
            ? kc + krow * 2048 + h * 128 + d
            : kr + krow * 1024 + h * 64 + (d - 128);
        *(short8_t*)(Kl + rr * 200 + d) = ld8(src);
      }
#pragma unroll
      for (int i = 0; i < 2; ++i) {
        int ch = i * 256 + tid;
        int jj = ch >> 4, d0 = (ch & 15) * 8;
        if (jj < nd) {
          union { short8_t v; __hip_bfloat16 hh[8]; } u;
          u.v = ld8(vcb + (size_t)(b * 2048 + 64 * (2 + jj)) * 2048 + h * 128 + d0);
#pragma unroll
          for (int q = 0; q < 8; ++q) {
            int dh = d0 + q;
            int swc = (jj >> 3) ^ (dh & 7);
            *(__hip_bfloat16*)(Vtb + dh * 128 + 16 * swc + 2 * (jj & 7)) = u.hh[q];
          }
        }
      }
    }
    __syncthreads();

    // ---- S = Q_cat @ K_cat^T ----
    f32x4_t sacc[4] = {};
    __builtin_amdgcn_s_setprio(1);
#pragma unroll
    for (int n = 0; n < 4; ++n)
#pragma unroll
      for (int c = 0; c < 6; ++c) {
        short8_t bfr = ld8(Kl + (16 * n + L) * 200 + 32 * c + 8 * hi);
        sacc[n] = __builtin_amdgcn_mfma_f32_16x16x32_bf16(qf[c], bfr, sacc[n], 0, 0, 0);
      }
    __builtin_amdgcn_s_setprio(0);

    // ---- mask + online softmax ----
    int rbase = q0 + w * 16 + 4 * hi;
    float p[4][4];
    float mt[4];
#pragma unroll
    for (int i = 0; i < 4; ++i) mt[i] = -1e30f;
#pragma unroll
    for (int n = 0; n < 4; ++n) {
      int col = L + 16 * n;
      int k = k0 + col;
#pragma unroll
      for (int i = 0; i < 4; ++i) {
        int rq = rbase + i;
        bool ok = compact ? (col < nd)
                          : ((k <= rq) && ((rq - k <= 256) || ((k & 63) == 0) || (k < 128)));
        float s = ok ? sacc[n][i] : -1e30f;
        p[n][i] = s;
        mt[i] = fmaxf(mt[i], s);
      }
    }
    for (int d = 1; d < 16; d <<= 1)
#pragma unroll
      for (int i = 0; i < 4; ++i) mt[i] = fmaxf(mt[i], __shfl_xor(mt[i], d, 64));
    float al[4], rs[4];
#pragma unroll
    for (int i = 0; i < 4; ++i) {
      float mnew = fmaxf(mrow[i], mt[i]);
      al[i] = __expf(mrow[i] - mnew);
      mrow[i] = mnew;
      rs[i] = 0.0f;
    }
#pragma unroll
    for (int n = 0; n < 4; ++n)
#pragma unroll
      for (int i = 0; i < 4; ++i) {
        float e = __expf(p[n][i] - mrow[i]);
        p[n][i] = e;
        rs[i] += e;
      }
    for (int d = 1; d < 16; d <<= 1)
#pragma unroll
      for (int i = 0; i < 4; ++i) rs[i] += __shfl_xor(rs[i], d, 64);
#pragma unroll
    for (int i = 0; i < 4; ++i) lrow[i] = lrow[i] * al[i] + rs[i];
#pragma unroll
    for (int n = 0; n < 8; ++n)
#pragma unroll
      for (int i = 0; i < 4; ++i) oacc[n][i] *= al[i];

    // ---- P -> LDS ----
#pragma unroll
    for (int n = 0; n < 4; ++n)
#pragma unroll
      for (int i = 0; i < 4; ++i)
        Pl[w][(4 * hi + i) * 72 + 16 * n + L] = __float2bfloat16(p[n][i]);
    __syncthreads();

    // ---- O += P @ V ----
    __builtin_amdgcn_s_setprio(1);
#pragma unroll
    for (int ks = 0; ks < 2; ++ks) {
      short8_t pa = ld8(Pl[w] + L * 72 + 32 * ks + 8 * hi);
#pragma unroll
      for (int n = 0; n < 8; ++n) {
        int vrow = 16 * n + L;
        int chunk = (4 * ks + hi) ^ (vrow & 7);
        short8_t bv = *(const short8_t*)(Vtb + vrow * 128 + 16 * chunk);
        oacc[n] = __builtin_amdgcn_mfma_f32_16x16x32_bf16(pa, bv, oacc[n], 0, 0, 0);
      }
    }
    __builtin_amdgcn_s_setprio(0);
    __syncthreads();
  }

  // ---- epilogue ----
#pragma unroll
  for (int n = 0; n < 8; ++n)
#pragma unroll
    for (int i = 0; i < 4; ++i) {
      int rq = q0 + w * 16 + 4 * hi + i;
      int cdh = 16 * n + L;
      float v = oacc[n][i] / lrow[i];
      ao[((size_t)b * T + rq) * 2048 + h * 128 + cdh] = __float2bfloat16(v);
    }
}

// ---------------- host ----------------
extern "C" void kernel_launch(void* const* d_in, const int* in_sizes, int n_in,
                              void* d_out, int out_size, void* d_ws, size_t ws_size,
                              hipStream_t stream) {
  const float* x     = (const float*)d_in[0];
  const float* w_q   = (const float*)d_in[1];
  const float* w_dkv = (const float*)d_in[2];
  const float* w_uk  = (const float*)d_in[3];
  const float* w_uv  = (const float*)d_in[4];
  const float* w_qp  = (const float*)d_in[5];
  const float* w_kp  = (const float*)d_in[6];
  const float* w_o   = (const float*)d_in[7];
  float* out = (float*)d_out;

  char* ws = (char*)d_ws;
  size_t off = 0;
  auto alloc = [&](size_t elems) {
    __hip_bfloat16* p = (__hip_bfloat16*)(ws + off);
    off += ((elems * 2 + 255) & ~(size_t)255);
    return p;
  };
  __hip_bfloat16* xb  = alloc(8388608);            // x bf16 [4096][2048]
  __hip_bfloat16* Bt1 = alloc(4608UL * 2048);      // [wq^T; wqp^T; wkp^T; wdkv^T]
  __hip_bfloat16* Bt2 = alloc(4096UL * 512);       // [wuk^T; wuv^T]
  __hip_bfloat16* woT = alloc(4194304);
  __hip_bfloat16* qcb = alloc(8388608);
  __hip_bfloat16* ckv = alloc(2097152);
  __hip_bfloat16* kcb = alloc(8388608);
  __hip_bfloat16* vcb = alloc(8388608);
  __hip_bfloat16* qrb = alloc(4194304);
  __hip_bfloat16* krb = alloc(4194304);
  __hip_bfloat16* aob = alloc(8388608);
  __hip_bfloat16* vT  = alloc(8388608);            // [32][128][2048]

  k_convert<<<4096, 256, 0, stream>>>(x, xb, 8388608);
  // Bt1 rows: 0 wq^T(2048), 2048 wqp^T(1024), 3072 wkp^T(1024), 4096 wdkv^T(512)
  k_transpose<<<32 * 32, 256, 0, stream>>>(w_q,   Bt1,               2048, 2048);
  k_transpose<<<32 * 16, 256, 0, stream>>>(w_qp,  Bt1 + 2048UL * 2048, 2048, 1024);
  k_transpose<<<32 * 16, 256, 0, stream>>>(w_kp,  Bt1 + 3072UL * 2048, 2048, 1024);
  k_transpose<<<32 * 8,  256, 0, stream>>>(w_dkv, Bt1 + 4096UL * 2048, 2048, 512);
  // Bt2 rows: 0 wuk^T(2048), 2048 wuv^T(2048); K=512
  k_transpose<<<8 * 32,  256, 0, stream>>>(w_uk,  Bt2,               512, 2048);
  k_transpose<<<8 * 32,  256, 0, stream>>>(w_uv,  Bt2 + 2048UL * 512, 512, 2048);
  k_transpose<<<32 * 32, 256, 0, stream>>>(w_o,   woT,               2048, 2048);

  k_gemm_proj1<<<36 * 32, 256, 0, stream>>>(xb, Bt1, qcb, qrb, krb, ckv);
  k_gemm_proj2<<<32 * 32, 256, 0, stream>>>(ckv, Bt2, kcb, vcb, vT);

  k_attn<<<1024, 256, 0, stream>>>(qcb, kcb, vcb, qrb, krb, vT, aob);

  k_gemm_bt<1><<<32 * 16, 256, 0, stream>>>(aob, woT, out, 4096, 2048, 2048, 1.0f);
}